// Round 11
// baseline (363.416 us; speedup 1.0000x reference)
//
#include <hip/hip_runtime.h>
#include <hip/hip_fp16.h>
#include <stdint.h>

// out[e] = edge_attr[e] / segsum(edge_attr, row)[col[e]]
//
// Counting-sort by 8192-wide node bucket, exact atomic-free scatter offsets.
// nt hints ONLY on truly-dead streams (round 10 win: L3 absorbs pairs).
// Round-11: reduce + gather were latency-serialized from register starvation
// (reduce VGPR=8 -> one 16B load in flight; gather VGPR=36 < the 64 needed
// for 16 concurrent table loads; measured ~220 cyc/load = bare L2 latency).
// Fix: __launch_bounds__(B,4) (128-VGPR budget) + explicit staged load
// batches (reduce: 8x16B -> 32 atomics; gather: 16 ushort raw loads).
//   P1 hist / P2 totals / P3 bases / P4 offsets / P5 scatter / P6 reduce /
//   P7 recip(f16 table) / P8 gather.
// Fallback (small ws): direct-atomic version.

typedef int      v4i __attribute__((ext_vector_type(4)));
typedef float    v4f __attribute__((ext_vector_type(4)));
typedef unsigned v4u __attribute__((ext_vector_type(4)));
using ull = unsigned long long;
using u16 = unsigned short;

#define BKT_BITS 13
#define BKT_W    (1 << BKT_BITS)      // 8192 nodes per bucket
#define NB       128                   // supports N <= 1,048,576
#define NMAX     (NB << BKT_BITS)
#define TILE     4096
#define BLOCK1   512
#define BLOCK2   512

// ---------------- fast path ----------------

__global__ __launch_bounds__(BLOCK1) void hist_kernel(
    const int* __restrict__ row, int* __restrict__ histG, int E)
{
    __shared__ int h[NB];
    const int t = threadIdx.x;
    const long base = (long)blockIdx.x * TILE;
    if (t < NB) h[t] = 0;
    __syncthreads();
    if (base + TILE <= (long)E) {
        #pragma unroll
        for (int k = 0; k < 2; ++k) {
            const long e0 = base + ((long)(k * BLOCK1 + t) << 2);
            const v4i rv = *reinterpret_cast<const v4i*>(row + e0);  // regular: row -> L3 for scatter
            atomicAdd(&h[rv.x >> BKT_BITS], 1);
            atomicAdd(&h[rv.y >> BKT_BITS], 1);
            atomicAdd(&h[rv.z >> BKT_BITS], 1);
            atomicAdd(&h[rv.w >> BKT_BITS], 1);
        }
    } else {
        for (int k = 0; k < 2; ++k) {
            const long e0 = base + ((long)(k * BLOCK1 + t) << 2);
            for (int j = 0; j < 4; ++j)
                if (e0 + j < (long)E) atomicAdd(&h[row[e0 + j] >> BKT_BITS], 1);
        }
    }
    __syncthreads();
    if (t < NB) histG[(size_t)blockIdx.x * NB + t] = h[t];
}

__global__ __launch_bounds__(256) void totals_kernel(
    const int* __restrict__ histG, int* __restrict__ totals, int nTiles)
{
    __shared__ int s[256];
    const int b = blockIdx.x;
    int acc = 0;
    for (int t = threadIdx.x; t < nTiles; t += 256)
        acc += histG[(size_t)t * NB + b];
    s[threadIdx.x] = acc;
    __syncthreads();
    for (int o = 128; o > 0; o >>= 1) {
        if (threadIdx.x < o) s[threadIdx.x] += s[threadIdx.x + o];
        __syncthreads();
    }
    if (threadIdx.x == 0) totals[b] = s[0];
}

__global__ __launch_bounds__(NB) void bases_kernel(
    const int* __restrict__ totals, int* __restrict__ bases)
{
    __shared__ int s[NB];
    const int t = threadIdx.x;
    const int rc = (totals[t] + 1) & ~1;      // even-rounded -> 16B-aligned regions
    s[t] = rc;
    __syncthreads();
    for (int off = 1; off < NB; off <<= 1) {
        const int v = (t >= off) ? s[t - off] : 0;
        __syncthreads();
        s[t] += v;
        __syncthreads();
    }
    bases[t] = s[t] - rc;
}

__global__ __launch_bounds__(256) void offsets_kernel(
    const int* __restrict__ histG, const int* __restrict__ bases,
    int* __restrict__ offG, int nTiles)
{
    __shared__ int s[256];
    const int b = blockIdx.x;
    const int seg = (nTiles + 255) >> 8;
    const int t0 = threadIdx.x * seg;
    int acc = 0;
    for (int k = 0; k < seg; ++k) {
        const int t = t0 + k;
        if (t < nTiles) acc += histG[(size_t)t * NB + b];
    }
    s[threadIdx.x] = acc;
    __syncthreads();
    for (int off = 1; off < 256; off <<= 1) {
        const int v = (threadIdx.x >= off) ? s[threadIdx.x - off] : 0;
        __syncthreads();
        s[threadIdx.x] += v;
        __syncthreads();
    }
    int run = bases[b] + s[threadIdx.x] - acc;     // exclusive base for my segment
    for (int k = 0; k < seg; ++k) {
        const int t = t0 + k;
        if (t < nTiles) {
            offG[(size_t)t * NB + b] = run;
            run += histG[(size_t)t * NB + b];
        }
    }
}

__global__ __launch_bounds__(BLOCK1) void scatter_kernel(
    const int* __restrict__ row, const float* __restrict__ attr,
    const int* __restrict__ offG, ull* __restrict__ pairsG, int E)
{
    __shared__ int cnt[NB];
    __shared__ int scanb[NB];
    __shared__ int gbase[NB];
    __shared__ ull pairs[TILE];                    // 32 KB

    const int  t    = threadIdx.x;
    const long base = (long)blockIdx.x * TILE;
    const bool full = (base + TILE <= (long)E);

    if (t < NB) cnt[t] = 0;
    __syncthreads();

    int r[8]; float a[8]; int rk[8];
    if (full) {
        #pragma unroll
        for (int k = 0; k < 2; ++k) {
            const long e0 = base + ((long)(k * BLOCK1 + t) << 2);
            const v4i rv = *reinterpret_cast<const v4i*>(row + e0);   // L3-hot from hist
            const v4f av = __builtin_nontemporal_load(reinterpret_cast<const v4f*>(attr + e0));
            r[k*4+0]=rv.x; r[k*4+1]=rv.y; r[k*4+2]=rv.z; r[k*4+3]=rv.w;
            a[k*4+0]=av.x; a[k*4+1]=av.y; a[k*4+2]=av.z; a[k*4+3]=av.w;
        }
        #pragma unroll
        for (int i = 0; i < 8; ++i)
            rk[i] = atomicAdd(&cnt[r[i] >> BKT_BITS], 1);
    } else {
        for (int k = 0; k < 2; ++k) {
            const long e0 = base + ((long)(k * BLOCK1 + t) << 2);
            for (int j = 0; j < 4; ++j) {
                const int i = k*4 + j;
                if (e0 + j < (long)E) {
                    r[i] = row[e0 + j]; a[i] = attr[e0 + j];
                    rk[i] = atomicAdd(&cnt[r[i] >> BKT_BITS], 1);
                } else r[i] = -1;
            }
        }
    }
    __syncthreads();

    // wave-0 exclusive scan of the 128 bucket counts (2 bins/lane)
    if (t < 64) {
        const int h0 = cnt[2*t], h1 = cnt[2*t+1];
        const int sum = h0 + h1;
        int x = sum;
        #pragma unroll
        for (int off = 1; off < 64; off <<= 1) {
            const int y = __shfl_up(x, off);
            if (t >= off) x += y;
        }
        const int excl = x - sum;
        scanb[2*t]   = excl;
        scanb[2*t+1] = excl + h0;
    }
    if (t < NB) gbase[t] = offG[(size_t)blockIdx.x * NB + t];   // exact, no atomic
    __syncthreads();

    #pragma unroll
    for (int i = 0; i < 8; ++i)
        if (r[i] >= 0)
            pairs[scanb[r[i] >> BKT_BITS] + rk[i]] =
                ((ull)__float_as_uint(a[i]) << 32) | (unsigned)r[i];
    __syncthreads();

    const int total = full ? TILE : (int)((long)E - base);
    for (int s = t; s < total; s += BLOCK1) {
        const ull p  = pairs[s];
        const int bb = (int)(((unsigned)p) >> BKT_BITS);
        const size_t dst = (size_t)gbase[bb] + (size_t)(s - scanb[bb]);
        pairsG[dst] = p;                           // REGULAR store -> L3 keeps it for reduce
    }
}

__global__ __launch_bounds__(BLOCK2, 4) void reduce_kernel(
    const ull* __restrict__ pairsG, const int* __restrict__ totals,
    const int* __restrict__ bases, float* __restrict__ partial, int nSplit)
{
    __shared__ float bins[BKT_W];                  // 32 KB
    const int b = blockIdx.x / nSplit;
    const int q = blockIdx.x % nSplit;
    for (int i = threadIdx.x; i < BKT_W; i += BLOCK2) bins[i] = 0.0f;
    __syncthreads();

    const int cnt = totals[b];
    const ull* src = pairsG + (size_t)bases[b];    // even base -> 16B aligned

    // 16 pairs per iteration: stage 8x16B loads, then 32 LDS atomics
    const int Q16 = cnt >> 4;
    for (int i = q * BLOCK2 + threadIdx.x; i < Q16; i += nSplit * BLOCK2) {
        const v4u* p = reinterpret_cast<const v4u*>(src + ((size_t)i << 4));
        v4u v[8];
        #pragma unroll
        for (int k = 0; k < 8; ++k) v[k] = p[k];
        #pragma unroll
        for (int k = 0; k < 8; ++k) {
            atomicAdd(&bins[v[k].x & (BKT_W-1)], __uint_as_float(v[k].y));
            atomicAdd(&bins[v[k].z & (BKT_W-1)], __uint_as_float(v[k].w));
        }
    }
    const int tail0 = Q16 << 4;
    for (int o = tail0 + q * BLOCK2 + threadIdx.x; o < cnt; o += nSplit * BLOCK2) {
        const ull pp = src[o];
        atomicAdd(&bins[(unsigned)pp & (BKT_W-1)], __uint_as_float((unsigned)(pp >> 32)));
    }
    __syncthreads();

    float* dst = partial + (size_t)q * NMAX + ((size_t)b << BKT_BITS);
    for (int i = threadIdx.x; i < BKT_W; i += BLOCK2)
        dst[i] = bins[i];
}

__global__ void recip_kernel(const float* __restrict__ partial,
                             __half* __restrict__ rnorm16,
                             const int* __restrict__ Np, int nSplit) {
    const int N = *Np;
    const int stride = gridDim.x * blockDim.x;
    for (int i = blockIdx.x * blockDim.x + threadIdx.x; i < N; i += stride) {
        float s = 0.0f;
        for (int q = 0; q < nSplit; ++q) s += partial[(size_t)q * NMAX + i];
        rnorm16[i] = __float2half(1.0f / s);
    }
}

// ---------------- gather pass (f16 table, staged ushort loads) ----------------

__global__ __launch_bounds__(256, 4) void gather_scale_f16_kernel(
    const int* __restrict__ col, const float* __restrict__ attr,
    const __half* __restrict__ rn, float* __restrict__ out, int E)
{
    const u16* rnu = reinterpret_cast<const u16*>(rn);
    const int tid = blockIdx.x * blockDim.x + threadIdx.x;
    const int stride = gridDim.x * blockDim.x;
    const int E4 = E >> 2;
    const v4i* col4  = reinterpret_cast<const v4i*>(col);
    const v4f* attr4 = reinterpret_cast<const v4f*>(attr);
    v4f*       out4  = reinterpret_cast<v4f*>(out);

    int i = tid;
    for (; i + 3 * stride < E4; i += 4 * stride) {
        v4i c[4]; v4f a[4];
        #pragma unroll
        for (int k = 0; k < 4; ++k) c[k] = __builtin_nontemporal_load(col4 + i + k * stride);
        #pragma unroll
        for (int k = 0; k < 4; ++k) a[k] = __builtin_nontemporal_load(attr4 + i + k * stride);
        // stage all 16 raw table loads before any conversion (full MLP)
        u16 h[16];
        #pragma unroll
        for (int k = 0; k < 4; ++k) {
            h[k*4+0] = rnu[c[k].x];
            h[k*4+1] = rnu[c[k].y];
            h[k*4+2] = rnu[c[k].z];
            h[k*4+3] = rnu[c[k].w];
        }
        #pragma unroll
        for (int k = 0; k < 4; ++k) {
            v4f o;
            o.x = __half2float(__ushort_as_half(h[k*4+0])) * a[k].x;
            o.y = __half2float(__ushort_as_half(h[k*4+1])) * a[k].y;
            o.z = __half2float(__ushort_as_half(h[k*4+2])) * a[k].z;
            o.w = __half2float(__ushort_as_half(h[k*4+3])) * a[k].w;
            __builtin_nontemporal_store(o, out4 + i + k * stride);
        }
    }
    for (; i < E4; i += stride) {
        const v4i c = __builtin_nontemporal_load(col4 + i);
        const v4f a = __builtin_nontemporal_load(attr4 + i);
        v4f o;
        o.x = __half2float(rn[c.x]) * a.x; o.y = __half2float(rn[c.y]) * a.y;
        o.z = __half2float(rn[c.z]) * a.z; o.w = __half2float(rn[c.w]) * a.w;
        __builtin_nontemporal_store(o, out4 + i);
    }
    for (int e = (E4 << 2) + tid; e < E; e += stride)
        out[e] = __half2float(rn[col[e]]) * attr[e];
}

// ---------------- fallback path (f32, direct atomics) ----------------

__global__ void zero_ws_kernel(float* __restrict__ ws, const int* __restrict__ Np) {
    const int N = *Np;
    const int stride = gridDim.x * blockDim.x;
    for (int i = blockIdx.x * blockDim.x + threadIdx.x; i < N; i += stride)
        ws[i] = 0.0f;
}

__global__ void rowsum_atomic_kernel(const int* __restrict__ row,
                                     const float* __restrict__ attr,
                                     float* __restrict__ rowsum, int E) {
    const int tid = blockIdx.x * blockDim.x + threadIdx.x;
    const int stride = gridDim.x * blockDim.x;
    const int E4 = E >> 2;
    for (int i = tid; i < E4; i += stride) {
        const int4   r = reinterpret_cast<const int4*>(row)[i];
        const float4 a = reinterpret_cast<const float4*>(attr)[i];
        atomicAdd(&rowsum[r.x], a.x);
        atomicAdd(&rowsum[r.y], a.y);
        atomicAdd(&rowsum[r.z], a.z);
        atomicAdd(&rowsum[r.w], a.w);
    }
    for (int i = (E4 << 2) + tid; i < E; i += stride)
        atomicAdd(&rowsum[row[i]], attr[i]);
}

__global__ void recip_fallback_kernel(float* __restrict__ rowsum,
                                      const int* __restrict__ Np) {
    const int N = *Np;
    const int stride = gridDim.x * blockDim.x;
    for (int i = blockIdx.x * blockDim.x + threadIdx.x; i < N; i += stride)
        rowsum[i] = 1.0f / rowsum[i];
}

__global__ __launch_bounds__(256) void gather_scale_f32_kernel(
    const int* __restrict__ col, const float* __restrict__ attr,
    const float* __restrict__ rnorm, float* __restrict__ out, int E)
{
    const int tid = blockIdx.x * blockDim.x + threadIdx.x;
    const int stride = gridDim.x * blockDim.x;
    const int E4 = E >> 2;
    const v4i* col4  = reinterpret_cast<const v4i*>(col);
    const v4f* attr4 = reinterpret_cast<const v4f*>(attr);
    v4f*       out4  = reinterpret_cast<v4f*>(out);
    for (int i = tid; i < E4; i += stride) {
        const v4i c = __builtin_nontemporal_load(col4 + i);
        const v4f a = __builtin_nontemporal_load(attr4 + i);
        v4f o;
        o.x = rnorm[c.x] * a.x; o.y = rnorm[c.y] * a.y;
        o.z = rnorm[c.z] * a.z; o.w = rnorm[c.w] * a.w;
        __builtin_nontemporal_store(o, out4 + i);
    }
    for (int e = (E4 << 2) + tid; e < E; e += stride)
        out[e] = rnorm[col[e]] * attr[e];
}

// ---------------- launch ----------------

extern "C" void kernel_launch(void* const* d_in, const int* in_sizes, int n_in,
                              void* d_out, int out_size, void* d_ws, size_t ws_size,
                              hipStream_t stream) {
    const int*   edge_index = (const int*)d_in[0];     // [2, E]
    const float* edge_attr  = (const float*)d_in[1];   // [E]
    const int*   Np         = (const int*)d_in[2];     // scalar N (device)

    const int E = in_sizes[1];
    const int* row = edge_index;
    const int* col = edge_index + E;
    float* out = (float*)d_out;

    const int nTiles = (E + TILE - 1) / TILE;
    auto align256 = [](size_t x) { return (x + 255) & ~(size_t)255; };

    size_t off = 0;
    const size_t basesOff  = off; off += align256(NB * sizeof(int));
    const size_t totalsOff = off; off += align256(NB * sizeof(int));
    const size_t rn16Off   = off; off += align256((size_t)NMAX * sizeof(__half)); // 2 MB
    const size_t partOff   = off;
    const size_t histBytes = align256((size_t)nTiles * NB * sizeof(int));
    const size_t scanBytes = 2 * histBytes;                    // histG + offG
    const size_t pairsBytes = ((size_t)E + 2 * NB) * sizeof(ull);

    int nSplit = 0;
    size_t partRegion = 0;
    for (int c : {8, 4, 2, 1}) {
        size_t pr = (size_t)c * NMAX * sizeof(float);
        if (pr < scanBytes) pr = scanBytes;
        if (partOff + pr + pairsBytes <= ws_size) { nSplit = c; partRegion = pr; break; }
    }

    if (nSplit > 0) {
        int*    bases   = (int*)   ((char*)d_ws + basesOff);
        int*    totals  = (int*)   ((char*)d_ws + totalsOff);
        __half* rnorm16 = (__half*)((char*)d_ws + rn16Off);
        float*  partial = (float*) ((char*)d_ws + partOff);
        int*    histG   = (int*)   ((char*)d_ws + partOff);             // alias: dead
        int*    offG    = (int*)   ((char*)d_ws + partOff + histBytes); // before reduce
        ull*    pairs   = (ull*)   ((char*)d_ws + partOff + partRegion);

        hist_kernel           <<<nTiles, BLOCK1, 0, stream>>>(row, histG, E);
        totals_kernel         <<<NB, 256, 0, stream>>>(histG, totals, nTiles);
        bases_kernel          <<<1, NB, 0, stream>>>(totals, bases);
        offsets_kernel        <<<NB, 256, 0, stream>>>(histG, bases, offG, nTiles);
        scatter_kernel        <<<nTiles, BLOCK1, 0, stream>>>(row, edge_attr, offG, pairs, E);
        reduce_kernel         <<<NB * nSplit, BLOCK2, 0, stream>>>(pairs, totals, bases, partial, nSplit);
        recip_kernel          <<<1024, 256, 0, stream>>>(partial, rnorm16, Np, nSplit);
        gather_scale_f16_kernel<<<2048, 256, 0, stream>>>(col, edge_attr, rnorm16, out, E);
    } else {
        float* rowsum = (float*)d_ws;
        const int workE = (E + 3) >> 2;
        int gE = (workE + 255) / 256;
        if (gE > 2048) gE = 2048;
        zero_ws_kernel        <<<2048, 256, 0, stream>>>(rowsum, Np);
        rowsum_atomic_kernel  <<<gE, 256, 0, stream>>>(row, edge_attr, rowsum, E);
        recip_fallback_kernel <<<2048, 256, 0, stream>>>(rowsum, Np);
        gather_scale_f32_kernel<<<2048, 256, 0, stream>>>(col, edge_attr, rowsum, out, E);
    }
}